// Round 7
// baseline (410.800 us; speedup 1.0000x reference)
//
#include <hip/hip_runtime.h>

#define CI   128
#define TT   8192
#define CO   256
#define KW   9
#define NQ   5
#define PADL 4
#define KDIM (CI*KW)       // 1152
#define NSTEP 36           // K32 steps per q
#define NF (NQ*NSTEP)      // 180
#define BCO  128
#define BT   128
#define XROWS 136
#define XPITCH 136         // 272B rows: odd granule count -> octet-clean b128 reads
#define WSLOT 4096         // shorts: 128co x 32k = 8KB per ring slot, ring of 4

typedef __attribute__((ext_vector_type(8))) short short8;
typedef __attribute__((ext_vector_type(4))) float float4v;
typedef __attribute__((address_space(1))) const unsigned int ga_u32;
typedef __attribute__((address_space(3))) unsigned int la_u32;

static __device__ __forceinline__ short f2bf(float f) {
  union { float f; unsigned u; } c; c.f = f;
  unsigned u = c.u;
  return (short)((u + 0x7FFFu + ((u >> 16) & 1u)) >> 16);  // RNE
}

static __device__ __forceinline__ float tanh_fast(float z) {
  float e = __expf(2.f * z);
  return (e - 1.f) / (e + 1.f);
}

static __device__ __forceinline__ void gload_lds16(const short* g, short* l) {
  __builtin_amdgcn_global_load_lds((ga_u32*)g, (la_u32*)l, 16, 0, 0);
}

// ---- kernel 1: conv_weights (CO,CI,KW,NQ) fp32 -> wT[q][co][k*128+ci] bf16 ----
__global__ void selfonn_wtrans(const float* __restrict__ w, short* __restrict__ wT, int n) {
  int o = blockIdx.x * 256 + threadIdx.x;
  if (o >= n) return;
  int ci = o & (CI - 1);
  int k  = (o >> 7) % KW;
  int co = (o / KDIM) & (CO - 1);
  int q  = o / (KDIM * CO);
  wT[o] = f2bf(w[((co * CI + ci) * KW + k) * NQ + q]);
}

// ---- kernel 2: fused implicit-GEMM conv + nonlinearities + weighted sum ----
// 128x128 tile, 4 waves (64x64 each), 2 blocks/CU. Pipelined phase:
// stage(fi+3) -> vmcnt(4) -> BAR1 -> ds_read frags(fi+1) -> MFMA(fi) [no lgkm
// stall; reads drain under MFMA] -> [epi] -> BAR2.
__global__ __launch_bounds__(256, 2) void selfonn_main(
    const float* __restrict__ x, const short* __restrict__ wT,
    const float* __restrict__ probs, float* __restrict__ out) {

  __shared__ __align__(16) short xs[XROWS][XPITCH];   // 36992 B
  __shared__ __align__(16) short ws[4][WSLOT];        // 32768 B, slot-swizzled
  __shared__ float opw[BCO][NQ];                      // 2560 B

  const int tid  = threadIdx.x;
  const int lane = tid & 63;
  const int wid  = tid >> 6;   // 0..3
  const int wm   = wid >> 1;   // co half
  const int wt   = wid & 1;    // t half
  const int l15  = lane & 15;
  const int lg   = lane >> 4;  // 0..3
  const int b    = blockIdx.z;
  const int co0  = blockIdx.y * BCO;
  const int t0   = blockIdx.x * BT;

  // operator softmax -> LDS
  if (tid < BCO) {
    float p[NQ];
    float mx = -1e30f;
    #pragma unroll
    for (int j = 0; j < NQ; ++j) { p[j] = probs[(co0 + tid) * NQ + j]; mx = fmaxf(mx, p[j]); }
    float s = 0.f;
    #pragma unroll
    for (int j = 0; j < NQ; ++j) { p[j] = __expf(p[j] - mx); s += p[j]; }
    float inv = 1.0f / s;
    #pragma unroll
    for (int j = 0; j < NQ; ++j) opw[tid][j] = p[j] * inv;
  }

  // ---- weight staging addresses (inverse-swizzled global source) ----
  // granule G holds ws row co_l=G>>2 phys slot G&3; logical kslot=(G-(G>>3))&3
  int soff0, soff1;
  {
    int G0 = tid, G1 = 256 + tid;
    soff0 = (G0 >> 2) * KDIM + (((G0 - (G0 >> 3)) & 3) << 3);
    soff1 = (G1 >> 2) * KDIM + (((G1 - (G1 >> 3)) & 3) << 3);
  }
  const int sdst0 = (wid * 64) * 8;          // shorts; HW adds lane*16B
  const int sdst1 = (256 + wid * 64) * 8;
  const short* wTb = wT + (size_t)co0 * KDIM;

  // prologue: stage steps 0,1,2 into slots 0,1,2 (overlaps xs staging)
  #pragma unroll
  for (int ps = 0; ps < 3; ++ps) {
    gload_lds16(wTb + ps * 32 + soff0, &ws[ps][0] + sdst0);
    gload_lds16(wTb + ps * 32 + soff1, &ws[ps][0] + sdst1);
  }

  // stage x tile once (t-transposed, bf16): xs[tl][ci] = x[b][ci][t0-4+tl]
  const float* xb = x + (size_t)b * CI * TT;
  #pragma unroll
  for (int it = 0; it < 17; ++it) {
    int cell = tid + it * 256;          // 0..4351
    int ci = cell & (CI - 1);
    int tc = cell >> 7;                 // 0..33
    int tg = t0 - PADL + tc * 4;
    float4v v = {0.f, 0.f, 0.f, 0.f};
    if (tg >= 0 && tg <= TT - 4)
      v = *(const float4v*)(xb + (size_t)ci * TT + tg);
    int tl = tc * 4;
    xs[tl + 0][ci] = f2bf(v[0]);
    xs[tl + 1][ci] = f2bf(v[1]);
    xs[tl + 2][ci] = f2bf(v[2]);
    xs[tl + 3][ci] = f2bf(v[3]);
  }

  // ---- ds_read offset precompute (shorts) ----
  int afo[4], bfo[4];
  #pragma unroll
  for (int m = 0; m < 4; ++m) {
    int co = wm * 64 + m * 16 + l15;
    afo[m] = co * 32 + (((lg + (co >> 1)) & 3) << 3);
  }
  #pragma unroll
  for (int n = 0; n < 4; ++n)
    bfo[n] = (wt * 64 + n * 16 + l15) * XPITCH + (lg << 3);

  float4v oacc[4][4];
  float4v acc[4][4];
  #pragma unroll
  for (int m = 0; m < 4; ++m)
    #pragma unroll
    for (int n = 0; n < 4; ++n) {
      oacc[m][n] = (float4v){0.f, 0.f, 0.f, 0.f};
      acc[m][n]  = (float4v){0.f, 0.f, 0.f, 0.f};
    }

  __syncthreads();   // drains prologue stages + xs/opw writes

  // initial frags(0): slot 0, sq=0 (k=0, ci0=0)
  short8 afA[4], bfA[4], afB[4], bfB[4];
  #pragma unroll
  for (int m = 0; m < 4; ++m) afA[m] = *(const short8*)(&ws[0][0] + afo[m]);
  #pragma unroll
  for (int n = 0; n < 4; ++n) bfA[n] = *(const short8*)(&xs[0][0] + bfo[n]);

  int sq = 0, q = 0;
  int s_step = 3, s_qoff = 0;   // stage cursor = fi+3

  #define BODY(RSLOT, SSLOT, DOEPI, DOSTAGE, VMASM, CAF, CBF, NAF, NBF) \
    {                                                                  \
      /* 1. stage(fi+3) */                                             \
      if (DOSTAGE) {                                                   \
        const short* wp = wTb + s_qoff + s_step * 32;                  \
        gload_lds16(wp + soff0, &ws[SSLOT][0] + sdst0);                \
        gload_lds16(wp + soff1, &ws[SSLOT][0] + sdst1);                \
        if (++s_step == NSTEP) { s_step = 0; s_qoff += CO * KDIM; }    \
      }                                                                \
      /* 2. counted wait: confirms stage(fi+1) retired */              \
      asm volatile(VMASM ::: "memory");                                \
      /* 3. slot fi+1 now visible to all waves */                      \
      __builtin_amdgcn_s_barrier();                                    \
      __builtin_amdgcn_sched_barrier(0);                               \
      /* 4. prefetch frags(fi+1); drain under MFMA cluster */          \
      {                                                                \
        int sqn = (sq == NSTEP - 1) ? 0 : sq + 1;                      \
        const short* nb = &ws[RSLOT][0];                               \
        _Pragma("unroll") for (int m = 0; m < 4; ++m)                  \
          NAF[m] = *(const short8*)(nb + afo[m]);                      \
        const short* xp = &xs[0][0] + (sqn >> 2) * XPITCH + ((sqn & 3) << 5); \
        _Pragma("unroll") for (int n = 0; n < 4; ++n)                  \
          NBF[n] = *(const short8*)(xp + bfo[n]);                      \
      }                                                                \
      __builtin_amdgcn_sched_barrier(0);                               \
      /* 5. MFMA(fi) on frags read LAST phase (no lgkm stall) */       \
      __builtin_amdgcn_s_setprio(1);                                   \
      _Pragma("unroll") for (int m = 0; m < 4; ++m)                    \
        _Pragma("unroll") for (int n = 0; n < 4; ++n)                  \
          acc[m][n] = __builtin_amdgcn_mfma_f32_16x16x32_bf16(         \
              CAF[m], CBF[n], acc[m][n], 0, 0, 0);                     \
      __builtin_amdgcn_s_setprio(0);                                   \
      /* 6. epilogue at q-boundary */                                  \
      if (DOEPI && sq == NSTEP - 1) {                                  \
        _Pragma("unroll") for (int m = 0; m < 4; ++m) {                \
          _Pragma("unroll") for (int jj = 0; jj < 4; ++jj) {           \
            int co_l = wm * 64 + m * 16 + lg * 4 + jj;                 \
            float wqv = opw[co_l][q];                                  \
            _Pragma("unroll") for (int n = 0; n < 4; ++n) {            \
              float z = acc[m][n][jj];                                 \
              float f;                                                 \
              if (q == 0)      f = z;                                  \
              else if (q == 1) f = __sinf(z);                          \
              else if (q == 2) f = __cosf(z);                          \
              else if (q == 3) f = tanh_fast(z);                       \
              else             f = __expf(fminf(fmaxf(z, -8.f), 8.f)); \
              oacc[m][n][jj] += wqv * f;                               \
              acc[m][n][jj] = 0.f;                                     \
            }                                                          \
          }                                                            \
        }                                                              \
        ++q; sq = 0;                                                   \
      } else {                                                         \
        ++sq;                                                          \
      }                                                                \
      /* 7. all reads of the retiring slot done before its re-stage */ \
      __builtin_amdgcn_s_barrier();                                    \
    }

  for (int u = 0; u < 44; ++u) {        // fi = 0..175
    BODY(1, 3, 0, 1, "s_waitcnt vmcnt(4)", afA, bfA, afB, bfB)
    BODY(2, 0, 0, 1, "s_waitcnt vmcnt(4)", afB, bfB, afA, bfA)
    BODY(3, 1, 0, 1, "s_waitcnt vmcnt(4)", afA, bfA, afB, bfB)
    BODY(0, 2, 1, 1, "s_waitcnt vmcnt(4)", afB, bfB, afA, bfA)
  }
  // tail fi = 176..179
  BODY(1, 3, 0, 1, "s_waitcnt vmcnt(4)", afA, bfA, afB, bfB)   // stages step 179
  BODY(2, 0, 0, 0, "s_waitcnt vmcnt(2)", afB, bfB, afA, bfA)
  BODY(3, 1, 0, 0, "s_waitcnt vmcnt(0)", afA, bfA, afB, bfB)
  BODY(0, 2, 1, 0, "s_waitcnt vmcnt(0)", afB, bfB, afA, bfA)   // epilogue q=4
  #undef BODY

  // store (B, CO, T) fp32
  float* ob = out + (size_t)(b * CO + co0) * TT;
  #pragma unroll
  for (int m = 0; m < 4; ++m) {
    #pragma unroll
    for (int jj = 0; jj < 4; ++jj) {
      int co_l = wm * 64 + m * 16 + lg * 4 + jj;
      int tcol = t0 + wt * 64 + l15;
      float* orow = ob + (size_t)co_l * TT + tcol;
      #pragma unroll
      for (int n = 0; n < 4; ++n)
        orow[n * 16] = oacc[m][n][jj];
    }
  }
}

extern "C" void kernel_launch(void* const* d_in, const int* in_sizes, int n_in,
                              void* d_out, int out_size, void* d_ws, size_t ws_size,
                              hipStream_t stream) {
  const float* x     = (const float*)d_in[0];
  const float* w     = (const float*)d_in[1];
  const float* probs = (const float*)d_in[2];
  float* out = (float*)d_out;
  short* wT  = (short*)d_ws;   // NQ*CO*KDIM*2 = 2.95 MB

  int nw = NQ * CO * KDIM;
  selfonn_wtrans<<<dim3((nw + 255) / 256), 256, 0, stream>>>(w, wT, nw);

  dim3 grid(TT / BT, CO / BCO, 16);
  selfonn_main<<<grid, 256, 0, stream>>>(x, wT, probs, out);
}

// Round 8
// 352.608 us; speedup vs baseline: 1.1650x; 1.1650x over previous
//
#include <hip/hip_runtime.h>

#define CI   128
#define TT   8192
#define CO   256
#define KW   9
#define NQ   5
#define PADL 4
#define KDIM (CI*KW)       // 1152
#define NSTEP 36           // K32 steps per q
#define NF (NQ*NSTEP)      // 180
#define BCO  128
#define BT   128
#define XROWS 136
#define XPITCH 136         // 272B rows: odd granule count -> octet-clean b128 reads

typedef __attribute__((ext_vector_type(8))) short short8;
typedef __attribute__((ext_vector_type(4))) float float4v;

static __device__ __forceinline__ short f2bf(float f) {
  union { float f; unsigned u; } c; c.f = f;
  unsigned u = c.u;
  return (short)((u + 0x7FFFu + ((u >> 16) & 1u)) >> 16);  // RNE
}

static __device__ __forceinline__ float tanh_fast(float z) {
  float e = __expf(2.f * z);
  return (e - 1.f) / (e + 1.f);
}

// ---- kernel 1: pack conv_weights (CO,CI,KW,NQ) fp32 into per-lane fragment
// stream: wpk[(((ch*NF+fi)*2+wm)*4+m)*512 + lane*8 + j] = bf16 w[co][ci][k][q]
// with co = ch*128+wm*64+m*16+(lane&15), ci = (step&3)*32+(lane>>4)*8+j,
// fi = q*NSTEP+step, k = step>>2. Wave reads are then perfectly coalesced
// 1KB global_load_dwordx4 streams, entirely L2-resident (2.95MB < 4MB/XCD).
__global__ void selfonn_wpack(const float* __restrict__ w, short* __restrict__ wpk, int n) {
  int o = blockIdx.x * 256 + threadIdx.x;
  if (o >= n) return;
  int j    = o & 7;
  int lane = (o >> 3) & 63;
  int m    = (o >> 9) & 3;
  int wm   = (o >> 11) & 1;
  int ft   = o >> 12;          // 0..2*NF-1
  int ch   = ft / NF;
  int fi   = ft - ch * NF;
  int q    = fi / NSTEP;
  int step = fi - q * NSTEP;
  int k    = step >> 2;
  int cib  = step & 3;
  int l15  = lane & 15;
  int lg   = lane >> 4;
  int co   = ch * 128 + wm * 64 + m * 16 + l15;
  int ci   = cib * 32 + lg * 8 + j;
  wpk[o] = f2bf(w[((co * CI + ci) * KW + k) * NQ + q]);
}

// ---- kernel 2: fused implicit-GEMM conv + nonlinearities + weighted sum ----
// Barrier-free main loop: x tile staged once in LDS (read-only after init);
// weights stream global->VGPR (L2-resident), software-pipelined depth-1.
__global__ __launch_bounds__(256, 2) void selfonn_main(
    const float* __restrict__ x, const short* __restrict__ wpk,
    const float* __restrict__ probs, float* __restrict__ out) {

  __shared__ __align__(16) short xs[XROWS][XPITCH];   // 36992 B
  __shared__ float opw[BCO][NQ];                      // 2560 B

  const int tid  = threadIdx.x;
  const int lane = tid & 63;
  const int wid  = tid >> 6;   // 0..3
  const int wm   = wid >> 1;   // co half
  const int wt   = wid & 1;    // t half
  const int l15  = lane & 15;
  const int lg   = lane >> 4;  // 0..3
  const int b    = blockIdx.z;
  const int ch   = blockIdx.y;          // co 128-half of 256
  const int co0  = ch * BCO;
  const int t0   = blockIdx.x * BT;

  // operator softmax -> LDS
  if (tid < BCO) {
    float p[NQ];
    float mx = -1e30f;
    #pragma unroll
    for (int j = 0; j < NQ; ++j) { p[j] = probs[(co0 + tid) * NQ + j]; mx = fmaxf(mx, p[j]); }
    float s = 0.f;
    #pragma unroll
    for (int j = 0; j < NQ; ++j) { p[j] = __expf(p[j] - mx); s += p[j]; }
    float inv = 1.0f / s;
    #pragma unroll
    for (int j = 0; j < NQ; ++j) opw[tid][j] = p[j] * inv;
  }

  // stage x tile once (t-transposed, bf16): xs[tl][ci] = x[b][ci][t0-4+tl]
  const float* xb = x + (size_t)b * CI * TT;
  #pragma unroll
  for (int it = 0; it < 17; ++it) {
    int cell = tid + it * 256;          // 0..4351
    int ci = cell & (CI - 1);
    int tc = cell >> 7;                 // 0..33
    int tg = t0 - PADL + tc * 4;
    float4v v = {0.f, 0.f, 0.f, 0.f};
    if (tg >= 0 && tg <= TT - 4)
      v = *(const float4v*)(xb + (size_t)ci * TT + tg);
    int tl = tc * 4;
    xs[tl + 0][ci] = f2bf(v[0]);
    xs[tl + 1][ci] = f2bf(v[1]);
    xs[tl + 2][ci] = f2bf(v[2]);
    xs[tl + 3][ci] = f2bf(v[3]);
  }

  // B-frag LDS offsets (shorts)
  int bfo[4];
  #pragma unroll
  for (int n = 0; n < 4; ++n)
    bfo[n] = (wt * 64 + n * 16 + l15) * XPITCH + (lg << 3);

  // wave's packed-weight stream pointer (shorts): fi=0 frag base
  const short* wp = wpk + ((size_t)(ch * NF) * 2 + wm) * 2048 + lane * 8;

  float4v oacc[4][4];
  float4v acc[4][4];
  #pragma unroll
  for (int m = 0; m < 4; ++m)
    #pragma unroll
    for (int n = 0; n < 4; ++n) {
      oacc[m][n] = (float4v){0.f, 0.f, 0.f, 0.f};
      acc[m][n]  = (float4v){0.f, 0.f, 0.f, 0.f};
    }

  __syncthreads();   // xs/opw ready; no further barriers

  short8 WA[4], WB[4], BA[4], BB[4];
  // prologue: frags(0)
  #pragma unroll
  for (int m = 0; m < 4; ++m) WA[m] = *(const short8*)(wp + m * 512);
  #pragma unroll
  for (int n = 0; n < 4; ++n) BA[n] = *(const short8*)(&xs[0][0] + bfo[n]);

  int sq = 0, q = 0;

  #define STEP(CW, CB, NW, NB, DOPF, DOEPI)                            \
    {                                                                  \
      if (DOPF) {                                                      \
        /* prefetch weight frags(fi+1): linear stream, +8KB per fi */  \
        wp += 4096;                                                    \
        _Pragma("unroll") for (int m = 0; m < 4; ++m)                  \
          NW[m] = *(const short8*)(wp + m * 512);                      \
        /* prefetch B frags(fi+1) from static xs */                    \
        int sqn = (sq == NSTEP - 1) ? 0 : sq + 1;                      \
        const short* xp = &xs[0][0] + (sqn >> 2) * XPITCH + ((sqn & 3) << 5); \
        _Pragma("unroll") for (int n = 0; n < 4; ++n)                  \
          NB[n] = *(const short8*)(xp + bfo[n]);                       \
      }                                                                \
      __builtin_amdgcn_s_setprio(1);                                   \
      _Pragma("unroll") for (int m = 0; m < 4; ++m)                    \
        _Pragma("unroll") for (int n = 0; n < 4; ++n)                  \
          acc[m][n] = __builtin_amdgcn_mfma_f32_16x16x32_bf16(         \
              CW[m], CB[n], acc[m][n], 0, 0, 0);                       \
      __builtin_amdgcn_s_setprio(0);                                   \
      if (DOEPI && sq == NSTEP - 1) {                                  \
        _Pragma("unroll") for (int m = 0; m < 4; ++m) {                \
          _Pragma("unroll") for (int jj = 0; jj < 4; ++jj) {           \
            int co_l = wm * 64 + m * 16 + lg * 4 + jj;                 \
            float wqv = opw[co_l][q];                                  \
            _Pragma("unroll") for (int n = 0; n < 4; ++n) {            \
              float z = acc[m][n][jj];                                 \
              float f;                                                 \
              if (q == 0)      f = z;                                  \
              else if (q == 1) f = __sinf(z);                          \
              else if (q == 2) f = __cosf(z);                          \
              else if (q == 3) f = tanh_fast(z);                       \
              else             f = __expf(fminf(fmaxf(z, -8.f), 8.f)); \
              oacc[m][n][jj] += wqv * f;                               \
              acc[m][n][jj] = 0.f;                                     \
            }                                                          \
          }                                                            \
        }                                                              \
        ++q; sq = 0;                                                   \
      } else {                                                         \
        ++sq;                                                          \
      }                                                                \
    }

  // fi = 0..177 (epilogues at odd fi = 35,71,107,143 hit the second copy)
  for (int u = 0; u < 89; ++u) {
    STEP(WA, BA, WB, BB, 1, 0)
    STEP(WB, BB, WA, BA, 1, 1)
  }
  // fi = 178 (prefetch 179), fi = 179 (no prefetch; epilogue q=4)
  STEP(WA, BA, WB, BB, 1, 0)
  STEP(WB, BB, WA, BA, 0, 1)
  #undef STEP

  // store (B, CO, T) fp32
  float* ob = out + (size_t)(b * CO + co0) * TT;
  #pragma unroll
  for (int m = 0; m < 4; ++m) {
    #pragma unroll
    for (int jj = 0; jj < 4; ++jj) {
      int co_l = wm * 64 + m * 16 + lg * 4 + jj;
      int tcol = t0 + wt * 64 + l15;
      float* orow = ob + (size_t)co_l * TT + tcol;
      #pragma unroll
      for (int n = 0; n < 4; ++n)
        orow[n * 16] = oacc[m][n][jj];
    }
  }
}

extern "C" void kernel_launch(void* const* d_in, const int* in_sizes, int n_in,
                              void* d_out, int out_size, void* d_ws, size_t ws_size,
                              hipStream_t stream) {
  const float* x     = (const float*)d_in[0];
  const float* w     = (const float*)d_in[1];
  const float* probs = (const float*)d_in[2];
  float* out = (float*)d_out;
  short* wpk = (short*)d_ws;   // NQ*CO*KDIM*2 = 2.95 MB

  int nw = NQ * CO * KDIM;     // 1,474,560
  selfonn_wpack<<<dim3((nw + 255) / 256), 256, 0, stream>>>(w, wpk, nw);

  dim3 grid(TT / BT, CO / BCO, 16);
  selfonn_main<<<grid, 256, 0, stream>>>(x, wpk, probs, out);
}